// Round 9
// baseline (147.468 us; speedup 1.0000x reference)
//
#include <hip/hip_runtime.h>

typedef unsigned int uint32;
typedef __attribute__((ext_vector_type(4))) float f32x4;
typedef __attribute__((ext_vector_type(8))) _Float16 halfx8;
typedef __attribute__((ext_vector_type(4))) uint32 uint32x4;

#define N_NODES 10000
#define N_EDGES 320000

// scales
#define SC_W1      0.17677669529663687f   // 1/sqrt(32)
#define SC_MLP1    0.35355339059327373f   // 1/sqrt(8)
#define SC_MLP2    0.125f                 // 1/sqrt(64)
#define INV_SQRT3  0.5773502691896258f
#define COS_MIX    0.9238795325112867f    // cos(pi/8)
#define SIN_CONV   0.04783542904563623f   // sin(pi/8) / sqrt(64)

// ws layout (identical footprint to round 8, proven to fit)
#define WS_FEATP 0        // [N][128] floats, planar: f0 | f1x | f1y | f1z
#define I_CNT    1280000  // [N+1]
#define I_OFF    1290016  // [N+1]  (mutated by reorder; gather uses off-cnt)
#define U_REC    1300032  // [E] uint4: {bf16(ea.y,ea.z), ea.w, ea.x, src}
#define U_WF     2580032  // 28 frags x 64 lanes x 4 uints
#define U_WBUF   2587200  // [E][64] packed bf16 pairs, CSR order; row[0..3] = es16 header pre-MLP

__device__ __forceinline__ uint32 f2bf(float x) {
    uint32 u = __float_as_uint(x);
    return (u + 0x7fffu + ((u >> 16) & 1u)) >> 16;
}
__device__ __forceinline__ uint32 pack_bf2(float a, float b) {
    return f2bf(a) | (f2bf(b) << 16);
}
__device__ __forceinline__ uint32 packh2(float a, float b) {
    _Float16 ha = (_Float16)a, hb = (_Float16)b;
    return (uint32)__builtin_bit_cast(unsigned short, ha) |
           ((uint32)__builtin_bit_cast(unsigned short, hb) << 16);
}
__device__ __forceinline__ unsigned short h16(float x) {
    _Float16 h = (_Float16)x;
    return __builtin_bit_cast(unsigned short, h);
}
__device__ __forceinline__ float gelu_fast(float x) {
    float x2 = x * x;
    float z = x * __builtin_fmaf(0.03567740814f, x2, 0.7978845608f);
    float E = __builtin_amdgcn_exp2f(z * -2.885390082f);
    return x * __builtin_amdgcn_rcpf(1.0f + E);
}

// ================= K1: node_transform | csr_count | prep_frags ====
#define K1_NODE_BLOCKS 2500
#define K1_CNT_BLOCKS  1250
#define K1_PREP_BLOCKS 7
__global__ __launch_bounds__(256) void k1_fused(
        const float* __restrict__ x,
        const float* __restrict__ W1_0e, const float* __restrict__ W1_1o,
        const int* __restrict__ edge_dst, int* __restrict__ cnt,
        const float* __restrict__ Wm1, const float* __restrict__ Wm2,
        const float* __restrict__ Wp00, const float* __restrict__ Wp01,
        const float* __restrict__ Wp10, const float* __restrict__ Wp11,
        uint32* __restrict__ wf,
        float* __restrict__ featp, float* __restrict__ out) {
    int b = blockIdx.x;
    if (b < K1_NODE_BLOCKS) {
        __shared__ float xrow[4][128];
        int wv = threadIdx.x >> 6, lane = threadIdx.x & 63;
        int node = b * 4 + wv;
        float2 v = *(const float2*)(x + (size_t)node * 128 + lane * 2);
        xrow[wv][lane * 2]     = v.x;
        xrow[wv][lane * 2 + 1] = v.y;
        __syncthreads();
        const float* sx = xrow[wv];
        int w = lane;
        float f0 = 0.f, f1x = 0.f, f1y = 0.f, f1z = 0.f;
#pragma unroll
        for (int u = 0; u < 32; ++u) {
            float w0 = W1_0e[u * 64 + w];
            float w1 = W1_1o[u * 64 + w];
            f0  += sx[u] * w0;
            f1x += sx[32 + u * 3 + 0] * w1;
            f1y += sx[32 + u * 3 + 1] * w1;
            f1z += sx[32 + u * 3 + 2] * w1;
        }
        f0 *= SC_W1; f1x *= SC_W1; f1y *= SC_W1; f1z *= SC_W1;
        if (w < 32) {
            featp[node * 128 + w]      = f0;
            featp[node * 128 + 32 + w] = f1x;
            featp[node * 128 + 64 + w] = f1y;
            featp[node * 128 + 96 + w] = f1z;
        } else {
            int ww = w - 32;
            out[node * 128 + ww] = COS_MIX * f0;
            out[node * 128 + 32 + ww * 3 + 0] = COS_MIX * f1x;
            out[node * 128 + 32 + ww * 3 + 1] = COS_MIX * f1y;
            out[node * 128 + 32 + ww * 3 + 2] = COS_MIX * f1z;
        }
    } else if (b < K1_NODE_BLOCKS + K1_CNT_BLOCKS) {
        int e = (b - K1_NODE_BLOCKS) * 256 + threadIdx.x;
        atomicAdd(&cnt[edge_dst[e]], 1);
    } else {
        int gid = (b - K1_NODE_BLOCKS - K1_CNT_BLOCKS) * 256 + threadIdx.x;
        int f = gid >> 6, lane = gid & 63;
        int kq = (lane >> 4) * 8;
        int c15 = lane & 15;
        float vals[8];
        if (f < 4) {
            int c = 16 * f + c15;
#pragma unroll
            for (int j = 0; j < 8; ++j) { int k = kq + j; vals[j] = (k < 8) ? Wm1[k * 64 + c] : 0.f; }
        } else if (f < 12) {
            int idx = f - 4, nt = idx >> 1, ks = idx & 1;
            int c = 16 * nt + c15;
#pragma unroll
            for (int j = 0; j < 8; ++j) { int k = 32 * ks + kq + j; vals[j] = Wm2[k * 64 + c]; }
        } else {
            int idx = f - 12, nt = idx >> 1, ks = idx & 1;
            int c = 16 * nt + c15;
            int u = c & 31, m = c >> 5;
            const float* W = (m == 0) ? Wp00 : (m == 1) ? Wp01 : (m == 2) ? Wp10 : Wp11;
            float sc = (m == 3) ? 0.125f * INV_SQRT3 : 0.125f;
#pragma unroll
            for (int j = 0; j < 8; ++j) { int k = 32 * ks + kq + j; vals[j] = W[k * 32 + u] * sc; }
        }
        uint32* o = wf + f * 256 + lane * 4;
#pragma unroll
        for (int w = 0; w < 4; ++w) o[w] = packh2(vals[2 * w], vals[2 * w + 1]);
    }
}

// ================= K2: csr_scan (single block, 1024 threads) =================
__global__ __launch_bounds__(1024) void csr_scan(const int* __restrict__ cnt,
                                                 int* __restrict__ off) {
    __shared__ int partial[1024];
    int t = threadIdx.x;
    const int CHUNK = 10;
    int base = t * CHUNK;
    int s = 0;
#pragma unroll
    for (int j = 0; j < CHUNK; ++j) {
        int idx = base + j;
        s += (idx < N_NODES) ? cnt[idx] : 0;
    }
    partial[t] = s;
    __syncthreads();
    for (int o = 1; o < 1024; o <<= 1) {
        int v = partial[t];
        int add = (t >= o) ? partial[t - o] : 0;
        __syncthreads();
        partial[t] = v + add;
        __syncthreads();
    }
    int run = (t > 0) ? partial[t - 1] : 0;
    for (int j = 0; j < CHUNK; ++j) {
        int idx = base + j;
        if (idx < N_NODES) {
            off[idx] = run;
            run += cnt[idx];
        }
    }
    if (t == 1023) off[N_NODES] = run;
}

// ================= K3: reorder — the ONLY scattered writes (36B/edge) ========
__global__ __launch_bounds__(256) void reorder(
        const float* __restrict__ edge_scalar, const float* __restrict__ edge_attr,
        const int* __restrict__ src_in, const int* __restrict__ dst_in,
        int* __restrict__ off,
        uint32* __restrict__ wbuf, uint4* __restrict__ rec) {
    int e = blockIdx.x * 256 + threadIdx.x;   // grid 1250 exact
    float4 p = *(const float4*)(edge_scalar + (size_t)e * 8);
    float4 q = *(const float4*)(edge_scalar + (size_t)e * 8 + 4);
    float4 av = *(const float4*)(edge_attr + (size_t)e * 4);
    int sn = src_in[e];
    int dn = dst_in[e];
    int pos = atomicAdd(&off[dn], 1);
    // f16-packed es header -> first 16B of this edge's wbuf row (A-fragment bits)
    uint4 h;
    h.x = packh2(p.x, p.y); h.y = packh2(p.z, p.w);
    h.z = packh2(q.x, q.y); h.w = packh2(q.z, q.w);
    *(uint4*)(wbuf + (size_t)pos * 64) = h;
    uint4 rv;
    rv.x = pack_bf2(av.y, av.z);
    rv.y = __float_as_uint(av.w);
    rv.z = __float_as_uint(av.x);
    rv.w = (uint32)sn;
    rec[pos] = rv;
}

// ================= K4: mlp_pass — index-free MFMA MLP, all-linear I/O ========
#define MLP_BLOCKS 2500
__global__ __launch_bounds__(256) void mlp_pass(const uint32* __restrict__ wf,
                                                uint32* __restrict__ wbuf) {
    __shared__ unsigned short sh[4][1024];   // per-wave 16x64 f16 tile, XOR-swizzled
    int lane = threadIdx.x & 63;
    int wvq = threadIdx.x >> 6;
    int wave_id = blockIdx.x * 4 + wvq;
    int kq = (lane >> 4) * 8;
    int r15 = lane & 15;

    const uint32x4* wfp = (const uint32x4*)wf;
    halfx8 wb1[4], wb2[4][2], wbp[8][2];
#pragma unroll
    for (int nt = 0; nt < 4; ++nt)
        wb1[nt] = __builtin_bit_cast(halfx8, wfp[nt * 64 + lane]);
#pragma unroll
    for (int nt = 0; nt < 4; ++nt)
#pragma unroll
        for (int ks = 0; ks < 2; ++ks)
            wb2[nt][ks] = __builtin_bit_cast(halfx8, wfp[(4 + nt * 2 + ks) * 64 + lane]);
#pragma unroll
    for (int nt = 0; nt < 8; ++nt)
#pragma unroll
        for (int ks = 0; ks < 2; ++ks)
            wbp[nt][ks] = __builtin_bit_cast(halfx8, wfp[(12 + nt * 2 + ks) * 64 + lane]);

    const f32x4 z4 = {0.f, 0.f, 0.f, 0.f};
    unsigned short* shw = sh[wvq];

    for (int g = wave_id; g < N_EDGES / 16; g += MLP_BLOCKS * 4) {
        int p0 = g * 16;

        // read the f16 es header planted by reorder (row-owned, same-wave RAW safe)
        halfx8 a0 = (halfx8)0;
        if (lane < 16) {
            uint4 h = *(const uint4*)(wbuf + (size_t)(p0 + lane) * 64);
            a0 = __builtin_bit_cast(halfx8, h);
        }

        // h1 GEMM
        f32x4 acc1[4];
#pragma unroll
        for (int nt = 0; nt < 4; ++nt)
            acc1[nt] = __builtin_amdgcn_mfma_f32_16x16x32_f16(a0, wb1[nt], z4, 0, 0, 0);
#pragma unroll
        for (int nt = 0; nt < 4; ++nt)
#pragma unroll
            for (int i = 0; i < 4; ++i) {
                float gv = gelu_fast(acc1[nt][i] * SC_MLP1);
                int rr = (lane >> 4) * 4 + i;
                int ix = rr * 64 + 16 * nt + r15;
                shw[ix ^ ((rr & 7) << 3)] = h16(gv);
            }
        halfx8 a1[2];
#pragma unroll
        for (int ks = 0; ks < 2; ++ks) {
            int ix = r15 * 64 + 32 * ks + kq;
            a1[ks] = __builtin_bit_cast(halfx8,
                       *(const uint32x4*)&shw[ix ^ ((r15 & 7) << 3)]);
        }

        // h2 GEMM
        f32x4 acc2[4];
#pragma unroll
        for (int nt = 0; nt < 4; ++nt) {
            acc2[nt] = __builtin_amdgcn_mfma_f32_16x16x32_f16(a1[0], wb2[nt][0], z4, 0, 0, 0);
            acc2[nt] = __builtin_amdgcn_mfma_f32_16x16x32_f16(a1[1], wb2[nt][1], acc2[nt], 0, 0, 0);
        }
#pragma unroll
        for (int nt = 0; nt < 4; ++nt)
#pragma unroll
            for (int i = 0; i < 4; ++i) {
                float gv = gelu_fast(acc2[nt][i] * SC_MLP2);
                int rr = (lane >> 4) * 4 + i;
                int ix = rr * 64 + 16 * nt + r15;
                shw[ix ^ ((rr & 7) << 3)] = h16(gv);
            }
        halfx8 a2[2];
#pragma unroll
        for (int ks = 0; ks < 2; ++ks) {
            int ix = r15 * 64 + 32 * ks + kq;
            a2[ks] = __builtin_bit_cast(halfx8,
                       *(const uint32x4*)&shw[ix ^ ((r15 & 7) << 3)]);
        }

        // projection GEMM
        f32x4 accp[8];
#pragma unroll
        for (int nt = 0; nt < 8; ++nt) {
            accp[nt] = __builtin_amdgcn_mfma_f32_16x16x32_f16(a2[0], wbp[nt][0], z4, 0, 0, 0);
            accp[nt] = __builtin_amdgcn_mfma_f32_16x16x32_f16(a2[1], wbp[nt][1], accp[nt], 0, 0, 0);
        }

        // overwrite rows linearly (4KB contiguous per wave-group); no eax fold
#pragma unroll
        for (int i = 0; i < 4; ++i) {
            int rr = (lane >> 4) * 4 + i;
            uint32* wrow = wbuf + (size_t)(p0 + rr) * 64 + r15;
            wrow[0]  = pack_bf2(accp[0][i], accp[2][i]);
            wrow[16] = pack_bf2(accp[1][i], accp[3][i]);
            wrow[32] = pack_bf2(accp[4][i], accp[6][i]);
            wrow[48] = pack_bf2(accp[5][i], accp[7][i]);
        }
    }
}

// ================= K5: gather (all-linear streams + featp table) =============
__global__ __launch_bounds__(256) void gather(const int* __restrict__ off,
                                              const int* __restrict__ cnt,
                                              const uint4* __restrict__ rec,
                                              const uint32* __restrict__ wbuf,
                                              const float* __restrict__ featp,
                                              const float* __restrict__ W2_0e,
                                              const float* __restrict__ W2_1o,
                                              float* __restrict__ out) {
    int wv = threadIdx.x >> 6;
    int lane = threadIdx.x & 63;
    int node = blockIdx.x * 4 + wv;
    int u = lane & 31;
    int half = lane >> 5;

    int end = __builtin_amdgcn_readfirstlane(off[node]);   // off mutated = end
    int beg = end - __builtin_amdgcn_readfirstlane(cnt[node]);

    float a0acc = 0.f, a1x = 0.f, a1y = 0.f, a1z = 0.f;
    int offA = u + half * 32, offB = 64 + u, offC = 96 + u;

    for (int i0 = beg; i0 < end; i0 += 64) {
        int nn = end - i0;
        if (nn > 64) nn = 64;
        int idx = i0 + ((lane < nn) ? lane : 0);
        uint4 rv = rec[idx];                       // coalesced batch of 64 records
        int yzv = (int)rv.x, ewv = (int)rv.y, exv = (int)rv.z, svv = (int)rv.w;
        for (int j0 = 0; j0 < nn; j0 += 4) {
            uint32 wl_[4];
            float fa_[4], fb_[4], fc_[4], ey_[4], ez_[4], ew_[4], ex_[4];
#pragma unroll
            for (int t = 0; t < 4; ++t) {
                int j = j0 + t;
                int jc = (j < nn) ? j : nn - 1;
                uint32 yz = (uint32)__builtin_amdgcn_readlane(yzv, jc);
                ey_[t] = __uint_as_float(yz << 16);
                ez_[t] = __uint_as_float(yz & 0xffff0000u);
                ew_[t] = __uint_as_float((uint32)__builtin_amdgcn_readlane(ewv, jc));
                ex_[t] = __uint_as_float((uint32)__builtin_amdgcn_readlane(exv, jc));
                int s  = __builtin_amdgcn_readlane(svv, jc);
                uint32 wl = wbuf[(size_t)(i0 + jc) * 64 + lane];   // linear stream
                wl_[t] = (j < nn) ? wl : 0u;
                const float* fp = featp + (size_t)s * 128;
                fa_[t] = fp[offA];
                fb_[t] = fp[offB];
                fc_[t] = fp[offC];
            }
#pragma unroll
            for (int t = 0; t < 4; ++t) {
                float wa = __uint_as_float(wl_[t] << 16) * ex_[t];   // eax applied here
                float wb = __uint_as_float(wl_[t] & 0xffff0000u);
                float va = half ? ey_[t] : 1.0f;
                float vb = half ? ez_[t] : 0.0f;
                float vc = half ? ew_[t] : 0.0f;
                float dot = fa_[t] * va + fb_[t] * vb + fc_[t] * vc;
                float w0s = half ? wb : wa;
                a0acc += w0s * dot;
                float m  = half ? wa : wb * fa_[t];
                float vx = half ? fa_[t] : ey_[t];
                float vy = half ? fb_[t] : ez_[t];
                float vz = half ? fc_[t] : ew_[t];
                a1x += m * vx; a1y += m * vy; a1z += m * vz;
            }
        }
    }

    __shared__ float red[4][256];
    float* r = red[wv];
    int c = (half << 5) + u;
    r[c] = a0acc;
    int b = 64 + c * 3;
    r[b] = a1x; r[b + 1] = a1y; r[b + 2] = a1z;
    __syncthreads();

    if (half == 0) {
        float acc = 0.f;
#pragma unroll 8
        for (int w = 0; w < 64; ++w) acc += r[w] * W2_0e[w * 32 + u];
        int o = node * 128 + u;
        out[o] = out[o] + SIN_CONV * acc;          // prefilled with COS_MIX*self
    } else {
        float c0 = 0.f, c1 = 0.f, c2 = 0.f;
#pragma unroll 8
        for (int w = 0; w < 64; ++w) {
            float bw = W2_1o[w * 32 + u];
            c0 += r[64 + w * 3 + 0] * bw;
            c1 += r[64 + w * 3 + 1] * bw;
            c2 += r[64 + w * 3 + 2] * bw;
        }
        int o = node * 128 + 32 + u * 3;
        out[o + 0] = out[o + 0] + SIN_CONV * c0;
        out[o + 1] = out[o + 1] + SIN_CONV * c1;
        out[o + 2] = out[o + 2] + SIN_CONV * c2;
    }
}

extern "C" void kernel_launch(void* const* d_in, const int* in_sizes, int n_in,
                              void* d_out, int out_size, void* d_ws, size_t ws_size,
                              hipStream_t stream) {
    const float* node_input  = (const float*)d_in[0];
    const float* edge_attr   = (const float*)d_in[1];
    const float* edge_scalar = (const float*)d_in[2];
    const float* W1_0e       = (const float*)d_in[3];
    const float* W1_1o       = (const float*)d_in[4];
    const float* W_mlp1      = (const float*)d_in[5];
    const float* W_mlp2      = (const float*)d_in[6];
    const float* Wp00        = (const float*)d_in[7];
    const float* Wp01        = (const float*)d_in[8];
    const float* Wp10        = (const float*)d_in[9];
    const float* Wp11        = (const float*)d_in[10];
    const float* W2_0e       = (const float*)d_in[11];
    const float* W2_1o       = (const float*)d_in[12];
    const int*   edge_src    = (const int*)d_in[13];
    const int*   edge_dst    = (const int*)d_in[14];
    float* ws   = (float*)d_ws;
    int*   wsI  = (int*)d_ws;
    uint32* wsU = (uint32*)d_ws;
    uint4* recp = (uint4*)(wsU + U_REC);
    float* outp = (float*)d_out;

    hipMemsetAsync(wsI + I_CNT, 0, (N_NODES + 1) * sizeof(int), stream);

    k1_fused<<<K1_NODE_BLOCKS + K1_CNT_BLOCKS + K1_PREP_BLOCKS, 256, 0, stream>>>(
        node_input, W1_0e, W1_1o, edge_dst, wsI + I_CNT,
        W_mlp1, W_mlp2, Wp00, Wp01, Wp10, Wp11, wsU + U_WF, ws + WS_FEATP, outp);
    csr_scan<<<1, 1024, 0, stream>>>(wsI + I_CNT, wsI + I_OFF);
    reorder<<<1250, 256, 0, stream>>>(edge_scalar, edge_attr, edge_src, edge_dst,
                                      wsI + I_OFF, wsU + U_WBUF, recp);
    mlp_pass<<<MLP_BLOCKS, 256, 0, stream>>>(wsU + U_WF, wsU + U_WBUF);
    gather<<<N_NODES / 4, 256, 0, stream>>>(wsI + I_OFF, wsI + I_CNT, recp,
                                            wsU + U_WBUF, ws + WS_FEATP,
                                            W2_0e, W2_1o, outp);
}

// Round 10
// 126.524 us; speedup vs baseline: 1.1655x; 1.1655x over previous
//
#include <hip/hip_runtime.h>

typedef unsigned int uint32;
typedef __attribute__((ext_vector_type(4))) float f32x4;
typedef __attribute__((ext_vector_type(8))) _Float16 halfx8;
typedef __attribute__((ext_vector_type(4))) uint32 uint32x4;

#define N_NODES 10000
#define N_EDGES 320000

// scales
#define SC_W1      0.17677669529663687f   // 1/sqrt(32)
#define SC_MLP1    0.35355339059327373f   // 1/sqrt(8)
#define SC_MLP2    0.125f                 // 1/sqrt(64)
#define INV_SQRT3  0.5773502691896258f
#define COS_MIX    0.9238795325112867f    // cos(pi/8)
#define SIN_CONV   0.04783542904563623f   // sin(pi/8) / sqrt(64)

// ws layout
#define WS_FEATP 0        // [N][128] floats, planar: f0 | f1x | f1y | f1z
#define I_CNT    1280000  // [N+1]
#define I_OFF    1290016  // [N+1]  (mutated by mlp_scatter; gather uses off-cnt)
#define U_REC    1300032  // [E] uint4: {ea.y, ea.z, ea.w bits, src}
#define U_WF     2580032  // 28 frags x 64 lanes x 4 uints
#define U_WBUF   2587200  // [E][64] packed bf16 pairs, CSR-position order

__device__ __forceinline__ uint32 f2bf(float x) {
    uint32 u = __float_as_uint(x);
    return (u + 0x7fffu + ((u >> 16) & 1u)) >> 16;
}
__device__ __forceinline__ uint32 pack_bf2(float a, float b) {
    return f2bf(a) | (f2bf(b) << 16);
}
__device__ __forceinline__ uint32 packh2(float a, float b) {
    _Float16 ha = (_Float16)a, hb = (_Float16)b;
    return (uint32)__builtin_bit_cast(unsigned short, ha) |
           ((uint32)__builtin_bit_cast(unsigned short, hb) << 16);
}
__device__ __forceinline__ unsigned short h16(float x) {
    _Float16 h = (_Float16)x;
    return __builtin_bit_cast(unsigned short, h);
}
__device__ __forceinline__ float gelu_fast(float x) {
    float x2 = x * x;
    float z = x * __builtin_fmaf(0.03567740814f, x2, 0.7978845608f);
    float E = __builtin_amdgcn_exp2f(z * -2.885390082f);
    return x * __builtin_amdgcn_rcpf(1.0f + E);
}

// ================= K1: node_transform | csr_count | prep_frags ====
#define K1_NODE_BLOCKS 2500
#define K1_CNT_BLOCKS  1250
#define K1_PREP_BLOCKS 7
__global__ __launch_bounds__(256) void k1_fused(
        const float* __restrict__ x,
        const float* __restrict__ W1_0e, const float* __restrict__ W1_1o,
        const int* __restrict__ edge_dst, int* __restrict__ cnt,
        const float* __restrict__ Wm1, const float* __restrict__ Wm2,
        const float* __restrict__ Wp00, const float* __restrict__ Wp01,
        const float* __restrict__ Wp10, const float* __restrict__ Wp11,
        uint32* __restrict__ wf,
        float* __restrict__ featp, float* __restrict__ out) {
    int b = blockIdx.x;
    if (b < K1_NODE_BLOCKS) {
        __shared__ float xrow[4][128];
        int wv = threadIdx.x >> 6, lane = threadIdx.x & 63;
        int node = b * 4 + wv;
        float2 v = *(const float2*)(x + (size_t)node * 128 + lane * 2);
        xrow[wv][lane * 2]     = v.x;
        xrow[wv][lane * 2 + 1] = v.y;
        __syncthreads();
        const float* sx = xrow[wv];
        int w = lane;
        float f0 = 0.f, f1x = 0.f, f1y = 0.f, f1z = 0.f;
#pragma unroll
        for (int u = 0; u < 32; ++u) {
            float w0 = W1_0e[u * 64 + w];
            float w1 = W1_1o[u * 64 + w];
            f0  += sx[u] * w0;
            f1x += sx[32 + u * 3 + 0] * w1;
            f1y += sx[32 + u * 3 + 1] * w1;
            f1z += sx[32 + u * 3 + 2] * w1;
        }
        f0 *= SC_W1; f1x *= SC_W1; f1y *= SC_W1; f1z *= SC_W1;
        if (w < 32) {
            featp[node * 128 + w]      = f0;
            featp[node * 128 + 32 + w] = f1x;
            featp[node * 128 + 64 + w] = f1y;
            featp[node * 128 + 96 + w] = f1z;
        } else {
            int ww = w - 32;
            out[node * 128 + ww] = COS_MIX * f0;
            out[node * 128 + 32 + ww * 3 + 0] = COS_MIX * f1x;
            out[node * 128 + 32 + ww * 3 + 1] = COS_MIX * f1y;
            out[node * 128 + 32 + ww * 3 + 2] = COS_MIX * f1z;
        }
    } else if (b < K1_NODE_BLOCKS + K1_CNT_BLOCKS) {
        int e = (b - K1_NODE_BLOCKS) * 256 + threadIdx.x;
        atomicAdd(&cnt[edge_dst[e]], 1);
    } else {
        int gid = (b - K1_NODE_BLOCKS - K1_CNT_BLOCKS) * 256 + threadIdx.x;
        int f = gid >> 6, lane = gid & 63;
        int kq = (lane >> 4) * 8;
        int c15 = lane & 15;
        float vals[8];
        if (f < 4) {
            int c = 16 * f + c15;
#pragma unroll
            for (int j = 0; j < 8; ++j) { int k = kq + j; vals[j] = (k < 8) ? Wm1[k * 64 + c] : 0.f; }
        } else if (f < 12) {
            int idx = f - 4, nt = idx >> 1, ks = idx & 1;
            int c = 16 * nt + c15;
#pragma unroll
            for (int j = 0; j < 8; ++j) { int k = 32 * ks + kq + j; vals[j] = Wm2[k * 64 + c]; }
        } else {
            int idx = f - 12, nt = idx >> 1, ks = idx & 1;
            int c = 16 * nt + c15;
            int u = c & 31, m = c >> 5;
            const float* W = (m == 0) ? Wp00 : (m == 1) ? Wp01 : (m == 2) ? Wp10 : Wp11;
            float sc = (m == 3) ? 0.125f * INV_SQRT3 : 0.125f;
#pragma unroll
            for (int j = 0; j < 8; ++j) { int k = 32 * ks + kq + j; vals[j] = W[k * 32 + u] * sc; }
        }
        uint32* o = wf + f * 256 + lane * 4;
#pragma unroll
        for (int w = 0; w < 4; ++w) o[w] = packh2(vals[2 * w], vals[2 * w + 1]);
    }
}

// ================= K2: csr_scan (single block, 1024 threads) =================
__global__ __launch_bounds__(1024) void csr_scan(const int* __restrict__ cnt,
                                                 int* __restrict__ off) {
    __shared__ int partial[1024];
    int t = threadIdx.x;
    const int CHUNK = 10;
    int base = t * CHUNK;
    int s = 0;
#pragma unroll
    for (int j = 0; j < CHUNK; ++j) {
        int idx = base + j;
        s += (idx < N_NODES) ? cnt[idx] : 0;
    }
    partial[t] = s;
    __syncthreads();
    for (int o = 1; o < 1024; o <<= 1) {
        int v = partial[t];
        int add = (t >= o) ? partial[t - o] : 0;
        __syncthreads();
        partial[t] = v + add;
        __syncthreads();
    }
    int run = (t > 0) ? partial[t - 1] : 0;
    for (int j = 0; j < CHUNK; ++j) {
        int idx = base + j;
        if (idx < N_NODES) {
            off[idx] = run;
            run += cnt[idx];
        }
    }
    if (t == 1023) off[N_NODES] = run;
}

// ================= K3: mlp_scatter — MFMA MLP in original order, ============
// scatter coefficient rows (full 256B contiguous per row via LDS transpose).
#define MLP_BLOCKS 1250
__global__ __launch_bounds__(256) void mlp_scatter(
        const float* __restrict__ edge_scalar, const float* __restrict__ edge_attr,
        const int* __restrict__ src_in, const int* __restrict__ dst_in,
        int* __restrict__ off,
        const uint32* __restrict__ wf,
        uint32* __restrict__ wbuf, uint4* __restrict__ rec) {
    __shared__ unsigned short sh[4][1024];   // per-wave 16x64 f16 tile, XOR-swizzled
    __shared__ uint32 ob[4][1024];           // per-wave 16 rows x 64 uints staging
    __shared__ float eaxs[4][16];
    __shared__ int   poss[4][16];
    int lane = threadIdx.x & 63;
    int wvq = threadIdx.x >> 6;
    int wave_id = blockIdx.x * 4 + wvq;
    int kq = (lane >> 4) * 8;
    int r15 = lane & 15;

    // preload all 28 weight fragments into registers (proven layout)
    const uint32x4* wfp = (const uint32x4*)wf;
    halfx8 wb1[4], wb2[4][2], wbp[8][2];
#pragma unroll
    for (int nt = 0; nt < 4; ++nt)
        wb1[nt] = __builtin_bit_cast(halfx8, wfp[nt * 64 + lane]);
#pragma unroll
    for (int nt = 0; nt < 4; ++nt)
#pragma unroll
        for (int ks = 0; ks < 2; ++ks)
            wb2[nt][ks] = __builtin_bit_cast(halfx8, wfp[(4 + nt * 2 + ks) * 64 + lane]);
#pragma unroll
    for (int nt = 0; nt < 8; ++nt)
#pragma unroll
        for (int ks = 0; ks < 2; ++ks)
            wbp[nt][ks] = __builtin_bit_cast(halfx8, wfp[(12 + nt * 2 + ks) * 64 + lane]);

    const f32x4 z4 = {0.f, 0.f, 0.f, 0.f};
    unsigned short* shw = sh[wvq];
    uint32* obw = ob[wvq];

    for (int g = wave_id; g < N_EDGES / 16; g += MLP_BLOCKS * 4) {
        int e0 = g * 16;

        halfx8 a0 = (halfx8)0;
        if (lane < 16) {
            int e = e0 + lane;
            const float* esp = edge_scalar + (size_t)e * 8;
            float4 p = *(const float4*)esp;
            float4 q = *(const float4*)(esp + 4);
            float4 av = *(const float4*)(edge_attr + (size_t)e * 4);
            int dn = dst_in[e];
            int sn = src_in[e];
            int pos = atomicAdd(&off[dn], 1);
            poss[wvq][lane] = pos;
            eaxs[wvq][lane] = av.x;
            uint4 rv;
            rv.x = __float_as_uint(av.y);
            rv.y = __float_as_uint(av.z);
            rv.z = __float_as_uint(av.w);
            rv.w = (uint32)sn;
            rec[pos] = rv;
            a0[0] = (_Float16)p.x; a0[1] = (_Float16)p.y;
            a0[2] = (_Float16)p.z; a0[3] = (_Float16)p.w;
            a0[4] = (_Float16)q.x; a0[5] = (_Float16)q.y;
            a0[6] = (_Float16)q.z; a0[7] = (_Float16)q.w;
        }

        // h1 GEMM
        f32x4 acc1[4];
#pragma unroll
        for (int nt = 0; nt < 4; ++nt)
            acc1[nt] = __builtin_amdgcn_mfma_f32_16x16x32_f16(a0, wb1[nt], z4, 0, 0, 0);
#pragma unroll
        for (int nt = 0; nt < 4; ++nt)
#pragma unroll
            for (int i = 0; i < 4; ++i) {
                float gv = gelu_fast(acc1[nt][i] * SC_MLP1);
                int rr = (lane >> 4) * 4 + i;
                int ix = rr * 64 + 16 * nt + r15;
                shw[ix ^ ((rr & 7) << 3)] = h16(gv);
            }
        halfx8 a1[2];
#pragma unroll
        for (int ks = 0; ks < 2; ++ks) {
            int ix = r15 * 64 + 32 * ks + kq;
            a1[ks] = __builtin_bit_cast(halfx8,
                       *(const uint32x4*)&shw[ix ^ ((r15 & 7) << 3)]);
        }

        // h2 GEMM
        f32x4 acc2[4];
#pragma unroll
        for (int nt = 0; nt < 4; ++nt) {
            acc2[nt] = __builtin_amdgcn_mfma_f32_16x16x32_f16(a1[0], wb2[nt][0], z4, 0, 0, 0);
            acc2[nt] = __builtin_amdgcn_mfma_f32_16x16x32_f16(a1[1], wb2[nt][1], acc2[nt], 0, 0, 0);
        }
#pragma unroll
        for (int nt = 0; nt < 4; ++nt)
#pragma unroll
            for (int i = 0; i < 4; ++i) {
                float gv = gelu_fast(acc2[nt][i] * SC_MLP2);
                int rr = (lane >> 4) * 4 + i;
                int ix = rr * 64 + 16 * nt + r15;
                shw[ix ^ ((rr & 7) << 3)] = h16(gv);
            }
        halfx8 a2[2];
#pragma unroll
        for (int ks = 0; ks < 2; ++ks) {
            int ix = r15 * 64 + 32 * ks + kq;
            a2[ks] = __builtin_bit_cast(halfx8,
                       *(const uint32x4*)&shw[ix ^ ((r15 & 7) << 3)]);
        }

        // projection GEMM
        f32x4 accp[8];
#pragma unroll
        for (int nt = 0; nt < 8; ++nt) {
            accp[nt] = __builtin_amdgcn_mfma_f32_16x16x32_f16(a2[0], wbp[nt][0], z4, 0, 0, 0);
            accp[nt] = __builtin_amdgcn_mfma_f32_16x16x32_f16(a2[1], wbp[nt][1], accp[nt], 0, 0, 0);
        }

        // fold ea.x, pack rows into LDS staging (same values as round 8)
#pragma unroll
        for (int i = 0; i < 4; ++i) {
            int rr = (lane >> 4) * 4 + i;
            float eax = eaxs[wvq][rr];
            uint32* orow = obw + rr * 64 + r15;
            orow[0]  = pack_bf2(accp[0][i] * eax, accp[2][i]);
            orow[16] = pack_bf2(accp[1][i] * eax, accp[3][i]);
            orow[32] = pack_bf2(accp[4][i] * eax, accp[6][i]);
            orow[48] = pack_bf2(accp[5][i] * eax, accp[7][i]);
        }
        // store full rows: each row = 16 lanes x dwordx4 = 256B contiguous
#pragma unroll
        for (int pass = 0; pass < 4; ++pass) {
            int r = pass * 4 + (lane >> 4);
            int pos = poss[wvq][r];
            uint32x4 v = *(const uint32x4*)&obw[r * 64 + r15 * 4];
            *(uint32x4*)(wbuf + (size_t)pos * 64 + r15 * 4) = v;
        }
    }
}

// ================= K4: gather (all-linear streams + featp table) =============
__global__ __launch_bounds__(256) void gather(const int* __restrict__ off,
                                              const int* __restrict__ cnt,
                                              const uint4* __restrict__ rec,
                                              const uint32* __restrict__ wbuf,
                                              const float* __restrict__ featp,
                                              const float* __restrict__ W2_0e,
                                              const float* __restrict__ W2_1o,
                                              float* __restrict__ out) {
    int wv = threadIdx.x >> 6;
    int lane = threadIdx.x & 63;
    int node = blockIdx.x * 4 + wv;
    int u = lane & 31;
    int half = lane >> 5;

    int end = __builtin_amdgcn_readfirstlane(off[node]);   // off mutated = end
    int beg = end - __builtin_amdgcn_readfirstlane(cnt[node]);

    float a0acc = 0.f, a1x = 0.f, a1y = 0.f, a1z = 0.f;
    int offA = u + half * 32, offB = 64 + u, offC = 96 + u;

    for (int i0 = beg; i0 < end; i0 += 64) {
        int nn = end - i0;
        if (nn > 64) nn = 64;
        int idx = i0 + ((lane < nn) ? lane : 0);
        uint4 rv = rec[idx];                       // coalesced batch of 64 records
        int eyv = (int)rv.x, ezv = (int)rv.y, ewv = (int)rv.z, svv = (int)rv.w;
        for (int j0 = 0; j0 < nn; j0 += 4) {
            uint32 wl_[4];
            float fa_[4], fb_[4], fc_[4], ey_[4], ez_[4], ew_[4];
#pragma unroll
            for (int t = 0; t < 4; ++t) {
                int j = j0 + t;
                int jc = (j < nn) ? j : nn - 1;
                ey_[t] = __uint_as_float((uint32)__builtin_amdgcn_readlane(eyv, jc));
                ez_[t] = __uint_as_float((uint32)__builtin_amdgcn_readlane(ezv, jc));
                ew_[t] = __uint_as_float((uint32)__builtin_amdgcn_readlane(ewv, jc));
                int s  = __builtin_amdgcn_readlane(svv, jc);
                uint32 wl = wbuf[(size_t)(i0 + jc) * 64 + lane];   // linear stream
                wl_[t] = (j < nn) ? wl : 0u;
                const float* fp = featp + (size_t)s * 128;
                fa_[t] = fp[offA];
                fb_[t] = fp[offB];
                fc_[t] = fp[offC];
            }
#pragma unroll
            for (int t = 0; t < 4; ++t) {
                float wa = __uint_as_float(wl_[t] << 16);
                float wb = __uint_as_float(wl_[t] & 0xffff0000u);
                float va = half ? ey_[t] : 1.0f;
                float vb = half ? ez_[t] : 0.0f;
                float vc = half ? ew_[t] : 0.0f;
                float dot = fa_[t] * va + fb_[t] * vb + fc_[t] * vc;
                float w0s = half ? wb : wa;
                a0acc += w0s * dot;
                float m  = half ? wa : wb * fa_[t];
                float vx = half ? fa_[t] : ey_[t];
                float vy = half ? fb_[t] : ez_[t];
                float vz = half ? fc_[t] : ew_[t];
                a1x += m * vx; a1y += m * vy; a1z += m * vz;
            }
        }
    }

    __shared__ float red[4][256];
    float* r = red[wv];
    int c = (half << 5) + u;
    r[c] = a0acc;
    int b = 64 + c * 3;
    r[b] = a1x; r[b + 1] = a1y; r[b + 2] = a1z;
    __syncthreads();

    if (half == 0) {
        float acc = 0.f;
#pragma unroll 8
        for (int w = 0; w < 64; ++w) acc += r[w] * W2_0e[w * 32 + u];
        int o = node * 128 + u;
        out[o] = out[o] + SIN_CONV * acc;          // prefilled with COS_MIX*self
    } else {
        float c0 = 0.f, c1 = 0.f, c2 = 0.f;
#pragma unroll 8
        for (int w = 0; w < 64; ++w) {
            float bw = W2_1o[w * 32 + u];
            c0 += r[64 + w * 3 + 0] * bw;
            c1 += r[64 + w * 3 + 1] * bw;
            c2 += r[64 + w * 3 + 2] * bw;
        }
        int o = node * 128 + 32 + u * 3;
        out[o + 0] = out[o + 0] + SIN_CONV * c0;
        out[o + 1] = out[o + 1] + SIN_CONV * c1;
        out[o + 2] = out[o + 2] + SIN_CONV * c2;
    }
}

extern "C" void kernel_launch(void* const* d_in, const int* in_sizes, int n_in,
                              void* d_out, int out_size, void* d_ws, size_t ws_size,
                              hipStream_t stream) {
    const float* node_input  = (const float*)d_in[0];
    const float* edge_attr   = (const float*)d_in[1];
    const float* edge_scalar = (const float*)d_in[2];
    const float* W1_0e       = (const float*)d_in[3];
    const float* W1_1o       = (const float*)d_in[4];
    const float* W_mlp1      = (const float*)d_in[5];
    const float* W_mlp2      = (const float*)d_in[6];
    const float* Wp00        = (const float*)d_in[7];
    const float* Wp01        = (const float*)d_in[8];
    const float* Wp10        = (const float*)d_in[9];
    const float* Wp11        = (const float*)d_in[10];
    const float* W2_0e       = (const float*)d_in[11];
    const float* W2_1o       = (const float*)d_in[12];
    const int*   edge_src    = (const int*)d_in[13];
    const int*   edge_dst    = (const int*)d_in[14];
    float* ws   = (float*)d_ws;
    int*   wsI  = (int*)d_ws;
    uint32* wsU = (uint32*)d_ws;
    uint4* recp = (uint4*)(wsU + U_REC);
    float* outp = (float*)d_out;

    hipMemsetAsync(wsI + I_CNT, 0, (N_NODES + 1) * sizeof(int), stream);

    k1_fused<<<K1_NODE_BLOCKS + K1_CNT_BLOCKS + K1_PREP_BLOCKS, 256, 0, stream>>>(
        node_input, W1_0e, W1_1o, edge_dst, wsI + I_CNT,
        W_mlp1, W_mlp2, Wp00, Wp01, Wp10, Wp11, wsU + U_WF, ws + WS_FEATP, outp);
    csr_scan<<<1, 1024, 0, stream>>>(wsI + I_CNT, wsI + I_OFF);
    mlp_scatter<<<MLP_BLOCKS, 256, 0, stream>>>(edge_scalar, edge_attr,
                                                edge_src, edge_dst, wsI + I_OFF,
                                                wsU + U_WF, wsU + U_WBUF, recp);
    gather<<<N_NODES / 4, 256, 0, stream>>>(wsI + I_OFF, wsI + I_CNT, recp,
                                            wsU + U_WBUF, ws + WS_FEATP,
                                            W2_0e, W2_1o, outp);
}

// Round 11
// 121.538 us; speedup vs baseline: 1.2133x; 1.0410x over previous
//
#include <hip/hip_runtime.h>

typedef unsigned int uint32;
typedef unsigned short ushrt;
typedef __attribute__((ext_vector_type(4))) float f32x4;
typedef __attribute__((ext_vector_type(2))) float f32x2;
typedef __attribute__((ext_vector_type(8))) _Float16 halfx8;
typedef __attribute__((ext_vector_type(4))) uint32 uint32x4;

#define N_NODES 10000
#define N_EDGES 320000

// scales
#define SC_W1      0.17677669529663687f   // 1/sqrt(32)
#define SC_MLP1    0.35355339059327373f   // 1/sqrt(8)
#define SC_MLP2    0.125f                 // 1/sqrt(64)
#define INV_SQRT3  0.5773502691896258f
#define COS_MIX    0.9238795325112867f    // cos(pi/8)
#define SIN_CONV   0.04783542904563623f   // sin(pi/8) / sqrt(64)

// ws layout
#define WS_FEATP 0        // [N][128] floats, planar: f0 | f1x | f1y | f1z
#define I_CNT    1280000  // [N+1]
#define I_OFF    1290016  // [N+1]  (mutated by mlp_scatter; gather uses off-cnt)
#define U_REC    1300032  // [E] uint4: {ea.y, ea.z, ea.w bits, src}
#define U_WF     2580032  // 28 frags x 64 lanes x 4 uints
#define U_WBUF   2587200  // [E][32] uints = [E][64] fp8-pairs (128B rows), CSR order

__device__ __forceinline__ uint32 packh2(float a, float b) {
    _Float16 ha = (_Float16)a, hb = (_Float16)b;
    return (uint32)__builtin_bit_cast(unsigned short, ha) |
           ((uint32)__builtin_bit_cast(unsigned short, hb) << 16);
}
__device__ __forceinline__ unsigned short h16(float x) {
    _Float16 h = (_Float16)x;
    return __builtin_bit_cast(unsigned short, h);
}
__device__ __forceinline__ unsigned short pack_fp8_2(float a, float b) {
    // OCP e4m3 pair in low 16 bits (byte0=a, byte1=b), HW round
    return (unsigned short)(__builtin_amdgcn_cvt_pk_fp8_f32(a, b, 0, false) & 0xffff);
}
__device__ __forceinline__ float gelu_fast(float x) {
    float x2 = x * x;
    float z = x * __builtin_fmaf(0.03567740814f, x2, 0.7978845608f);
    float E = __builtin_amdgcn_exp2f(z * -2.885390082f);
    return x * __builtin_amdgcn_rcpf(1.0f + E);
}

// ================= K1: node_transform | csr_count | prep_frags ====
#define K1_NODE_BLOCKS 2500
#define K1_CNT_BLOCKS  1250
#define K1_PREP_BLOCKS 7
__global__ __launch_bounds__(256) void k1_fused(
        const float* __restrict__ x,
        const float* __restrict__ W1_0e, const float* __restrict__ W1_1o,
        const int* __restrict__ edge_dst, int* __restrict__ cnt,
        const float* __restrict__ Wm1, const float* __restrict__ Wm2,
        const float* __restrict__ Wp00, const float* __restrict__ Wp01,
        const float* __restrict__ Wp10, const float* __restrict__ Wp11,
        uint32* __restrict__ wf,
        float* __restrict__ featp, float* __restrict__ out) {
    int b = blockIdx.x;
    if (b < K1_NODE_BLOCKS) {
        __shared__ float xrow[4][128];
        int wv = threadIdx.x >> 6, lane = threadIdx.x & 63;
        int node = b * 4 + wv;
        float2 v = *(const float2*)(x + (size_t)node * 128 + lane * 2);
        xrow[wv][lane * 2]     = v.x;
        xrow[wv][lane * 2 + 1] = v.y;
        __syncthreads();
        const float* sx = xrow[wv];
        int w = lane;
        float f0 = 0.f, f1x = 0.f, f1y = 0.f, f1z = 0.f;
#pragma unroll
        for (int u = 0; u < 32; ++u) {
            float w0 = W1_0e[u * 64 + w];
            float w1 = W1_1o[u * 64 + w];
            f0  += sx[u] * w0;
            f1x += sx[32 + u * 3 + 0] * w1;
            f1y += sx[32 + u * 3 + 1] * w1;
            f1z += sx[32 + u * 3 + 2] * w1;
        }
        f0 *= SC_W1; f1x *= SC_W1; f1y *= SC_W1; f1z *= SC_W1;
        if (w < 32) {
            featp[node * 128 + w]      = f0;
            featp[node * 128 + 32 + w] = f1x;
            featp[node * 128 + 64 + w] = f1y;
            featp[node * 128 + 96 + w] = f1z;
        } else {
            int ww = w - 32;
            out[node * 128 + ww] = COS_MIX * f0;
            out[node * 128 + 32 + ww * 3 + 0] = COS_MIX * f1x;
            out[node * 128 + 32 + ww * 3 + 1] = COS_MIX * f1y;
            out[node * 128 + 32 + ww * 3 + 2] = COS_MIX * f1z;
        }
    } else if (b < K1_NODE_BLOCKS + K1_CNT_BLOCKS) {
        int e = (b - K1_NODE_BLOCKS) * 256 + threadIdx.x;
        atomicAdd(&cnt[edge_dst[e]], 1);
    } else {
        int gid = (b - K1_NODE_BLOCKS - K1_CNT_BLOCKS) * 256 + threadIdx.x;
        int f = gid >> 6, lane = gid & 63;
        int kq = (lane >> 4) * 8;
        int c15 = lane & 15;
        float vals[8];
        if (f < 4) {
            int c = 16 * f + c15;
#pragma unroll
            for (int j = 0; j < 8; ++j) { int k = kq + j; vals[j] = (k < 8) ? Wm1[k * 64 + c] : 0.f; }
        } else if (f < 12) {
            int idx = f - 4, nt = idx >> 1, ks = idx & 1;
            int c = 16 * nt + c15;
#pragma unroll
            for (int j = 0; j < 8; ++j) { int k = 32 * ks + kq + j; vals[j] = Wm2[k * 64 + c]; }
        } else {
            int idx = f - 12, nt = idx >> 1, ks = idx & 1;
            int c = 16 * nt + c15;
            int u = c & 31, m = c >> 5;
            const float* W = (m == 0) ? Wp00 : (m == 1) ? Wp01 : (m == 2) ? Wp10 : Wp11;
            float sc = (m == 3) ? 0.125f * INV_SQRT3 : 0.125f;
#pragma unroll
            for (int j = 0; j < 8; ++j) { int k = 32 * ks + kq + j; vals[j] = W[k * 32 + u] * sc; }
        }
        uint32* o = wf + f * 256 + lane * 4;
#pragma unroll
        for (int w = 0; w < 4; ++w) o[w] = packh2(vals[2 * w], vals[2 * w + 1]);
    }
}

// ================= K2: csr_scan (single block, 1024 threads) =================
__global__ __launch_bounds__(1024) void csr_scan(const int* __restrict__ cnt,
                                                 int* __restrict__ off) {
    __shared__ int partial[1024];
    int t = threadIdx.x;
    const int CHUNK = 10;
    int base = t * CHUNK;
    int s = 0;
#pragma unroll
    for (int j = 0; j < CHUNK; ++j) {
        int idx = base + j;
        s += (idx < N_NODES) ? cnt[idx] : 0;
    }
    partial[t] = s;
    __syncthreads();
    for (int o = 1; o < 1024; o <<= 1) {
        int v = partial[t];
        int add = (t >= o) ? partial[t - o] : 0;
        __syncthreads();
        partial[t] = v + add;
        __syncthreads();
    }
    int run = (t > 0) ? partial[t - 1] : 0;
    for (int j = 0; j < CHUNK; ++j) {
        int idx = base + j;
        if (idx < N_NODES) {
            off[idx] = run;
            run += cnt[idx];
        }
    }
    if (t == 1023) off[N_NODES] = run;
}

// ================= K3: mlp_scatter — MFMA MLP, fp8 rows (128B, full-line) ====
#define MLP_BLOCKS 1250
__global__ __launch_bounds__(256) void mlp_scatter(
        const float* __restrict__ edge_scalar, const float* __restrict__ edge_attr,
        const int* __restrict__ src_in, const int* __restrict__ dst_in,
        int* __restrict__ off,
        const uint32* __restrict__ wf,
        uint32* __restrict__ wbuf, uint4* __restrict__ rec) {
    __shared__ unsigned short sh[4][1024];   // per-wave 16x64 f16 tile, XOR-swizzled
    __shared__ uint32 ob[4][512];            // per-wave 16 rows x 32 uints (fp8 rows)
    __shared__ float eaxs[4][16];
    __shared__ int   poss[4][16];
    int lane = threadIdx.x & 63;
    int wvq = threadIdx.x >> 6;
    int wave_id = blockIdx.x * 4 + wvq;
    int kq = (lane >> 4) * 8;
    int r15 = lane & 15;

    // preload all 28 weight fragments into registers (proven layout)
    const uint32x4* wfp = (const uint32x4*)wf;
    halfx8 wb1[4], wb2[4][2], wbp[8][2];
#pragma unroll
    for (int nt = 0; nt < 4; ++nt)
        wb1[nt] = __builtin_bit_cast(halfx8, wfp[nt * 64 + lane]);
#pragma unroll
    for (int nt = 0; nt < 4; ++nt)
#pragma unroll
        for (int ks = 0; ks < 2; ++ks)
            wb2[nt][ks] = __builtin_bit_cast(halfx8, wfp[(4 + nt * 2 + ks) * 64 + lane]);
#pragma unroll
    for (int nt = 0; nt < 8; ++nt)
#pragma unroll
        for (int ks = 0; ks < 2; ++ks)
            wbp[nt][ks] = __builtin_bit_cast(halfx8, wfp[(12 + nt * 2 + ks) * 64 + lane]);

    const f32x4 z4 = {0.f, 0.f, 0.f, 0.f};
    unsigned short* shw = sh[wvq];
    uint32* obw = ob[wvq];
    unsigned short* obw16 = (unsigned short*)obw;

    for (int g = wave_id; g < N_EDGES / 16; g += MLP_BLOCKS * 4) {
        int e0 = g * 16;

        halfx8 a0 = (halfx8)0;
        if (lane < 16) {
            int e = e0 + lane;
            const float* esp = edge_scalar + (size_t)e * 8;
            float4 p = *(const float4*)esp;
            float4 q = *(const float4*)(esp + 4);
            float4 av = *(const float4*)(edge_attr + (size_t)e * 4);
            int dn = dst_in[e];
            int sn = src_in[e];
            int pos = atomicAdd(&off[dn], 1);
            poss[wvq][lane] = pos;
            eaxs[wvq][lane] = av.x;
            uint4 rv;
            rv.x = __float_as_uint(av.y);
            rv.y = __float_as_uint(av.z);
            rv.z = __float_as_uint(av.w);
            rv.w = (uint32)sn;
            rec[pos] = rv;
            a0[0] = (_Float16)p.x; a0[1] = (_Float16)p.y;
            a0[2] = (_Float16)p.z; a0[3] = (_Float16)p.w;
            a0[4] = (_Float16)q.x; a0[5] = (_Float16)q.y;
            a0[6] = (_Float16)q.z; a0[7] = (_Float16)q.w;
        }

        // h1 GEMM
        f32x4 acc1[4];
#pragma unroll
        for (int nt = 0; nt < 4; ++nt)
            acc1[nt] = __builtin_amdgcn_mfma_f32_16x16x32_f16(a0, wb1[nt], z4, 0, 0, 0);
#pragma unroll
        for (int nt = 0; nt < 4; ++nt)
#pragma unroll
            for (int i = 0; i < 4; ++i) {
                float gv = gelu_fast(acc1[nt][i] * SC_MLP1);
                int rr = (lane >> 4) * 4 + i;
                int ix = rr * 64 + 16 * nt + r15;
                shw[ix ^ ((rr & 7) << 3)] = h16(gv);
            }
        halfx8 a1[2];
#pragma unroll
        for (int ks = 0; ks < 2; ++ks) {
            int ix = r15 * 64 + 32 * ks + kq;
            a1[ks] = __builtin_bit_cast(halfx8,
                       *(const uint32x4*)&shw[ix ^ ((r15 & 7) << 3)]);
        }

        // h2 GEMM
        f32x4 acc2[4];
#pragma unroll
        for (int nt = 0; nt < 4; ++nt) {
            acc2[nt] = __builtin_amdgcn_mfma_f32_16x16x32_f16(a1[0], wb2[nt][0], z4, 0, 0, 0);
            acc2[nt] = __builtin_amdgcn_mfma_f32_16x16x32_f16(a1[1], wb2[nt][1], acc2[nt], 0, 0, 0);
        }
#pragma unroll
        for (int nt = 0; nt < 4; ++nt)
#pragma unroll
            for (int i = 0; i < 4; ++i) {
                float gv = gelu_fast(acc2[nt][i] * SC_MLP2);
                int rr = (lane >> 4) * 4 + i;
                int ix = rr * 64 + 16 * nt + r15;
                shw[ix ^ ((rr & 7) << 3)] = h16(gv);
            }
        halfx8 a2[2];
#pragma unroll
        for (int ks = 0; ks < 2; ++ks) {
            int ix = r15 * 64 + 32 * ks + kq;
            a2[ks] = __builtin_bit_cast(halfx8,
                       *(const uint32x4*)&shw[ix ^ ((r15 & 7) << 3)]);
        }

        // projection GEMM
        f32x4 accp[8];
#pragma unroll
        for (int nt = 0; nt < 8; ++nt) {
            accp[nt] = __builtin_amdgcn_mfma_f32_16x16x32_f16(a2[0], wbp[nt][0], z4, 0, 0, 0);
            accp[nt] = __builtin_amdgcn_mfma_f32_16x16x32_f16(a2[1], wbp[nt][1], accp[nt], 0, 0, 0);
        }

        // fold ea.x, pack fp8 pairs into LDS staging (ushort per u-slot)
#pragma unroll
        for (int i = 0; i < 4; ++i) {
            int rr = (lane >> 4) * 4 + i;
            float eax = eaxs[wvq][rr];
            unsigned short* orow = obw16 + rr * 64;
            orow[r15]      = pack_fp8_2(accp[0][i] * eax, accp[2][i]);
            orow[16 + r15] = pack_fp8_2(accp[1][i] * eax, accp[3][i]);
            orow[32 + r15] = pack_fp8_2(accp[4][i] * eax, accp[6][i]);
            orow[48 + r15] = pack_fp8_2(accp[5][i] * eax, accp[7][i]);
        }
        // store full rows: each row = 8 lanes x dwordx4 = 128B = one L2 line
#pragma unroll
        for (int pass = 0; pass < 2; ++pass) {
            int r = pass * 8 + (lane >> 3);
            int pos = poss[wvq][r];
            int c4 = (lane & 7) * 4;
            uint32x4 v = *(const uint32x4*)&obw[r * 32 + c4];
            *(uint32x4*)(wbuf + (size_t)pos * 32 + c4) = v;
        }
    }
}

// ================= K4: gather (all-linear streams + featp table) =============
__global__ __launch_bounds__(256) void gather(const int* __restrict__ off,
                                              const int* __restrict__ cnt,
                                              const uint4* __restrict__ rec,
                                              const uint32* __restrict__ wbuf,
                                              const float* __restrict__ featp,
                                              const float* __restrict__ W2_0e,
                                              const float* __restrict__ W2_1o,
                                              float* __restrict__ out) {
    int wv = threadIdx.x >> 6;
    int lane = threadIdx.x & 63;
    int node = blockIdx.x * 4 + wv;
    int u = lane & 31;
    int half = lane >> 5;

    int end = __builtin_amdgcn_readfirstlane(off[node]);   // off mutated = end
    int beg = end - __builtin_amdgcn_readfirstlane(cnt[node]);

    float a0acc = 0.f, a1x = 0.f, a1y = 0.f, a1z = 0.f;
    int offA = u + half * 32, offB = 64 + u, offC = 96 + u;
    const ushrt* wbuf16 = (const ushrt*)wbuf;
    int uslot = (half << 5) + u;

    for (int i0 = beg; i0 < end; i0 += 64) {
        int nn = end - i0;
        if (nn > 64) nn = 64;
        int idx = i0 + ((lane < nn) ? lane : 0);
        uint4 rv = rec[idx];                       // coalesced batch of 64 records
        int eyv = (int)rv.x, ezv = (int)rv.y, ewv = (int)rv.z, svv = (int)rv.w;
        for (int j0 = 0; j0 < nn; j0 += 4) {
            uint32 wl_[4];
            float fa_[4], fb_[4], fc_[4], ey_[4], ez_[4], ew_[4];
#pragma unroll
            for (int t = 0; t < 4; ++t) {
                int j = j0 + t;
                int jc = (j < nn) ? j : nn - 1;
                ey_[t] = __uint_as_float((uint32)__builtin_amdgcn_readlane(eyv, jc));
                ez_[t] = __uint_as_float((uint32)__builtin_amdgcn_readlane(ezv, jc));
                ew_[t] = __uint_as_float((uint32)__builtin_amdgcn_readlane(ewv, jc));
                int s  = __builtin_amdgcn_readlane(svv, jc);
                uint32 wl = (uint32)wbuf16[(size_t)(i0 + jc) * 64 + uslot]; // linear 128B rows
                wl_[t] = (j < nn) ? wl : 0u;
                const float* fp = featp + (size_t)s * 128;
                fa_[t] = fp[offA];
                fb_[t] = fp[offB];
                fc_[t] = fp[offC];
            }
#pragma unroll
            for (int t = 0; t < 4; ++t) {
                f32x2 wab = __builtin_amdgcn_cvt_pk_f32_fp8((int)wl_[t], false);
                float wa = wab.x;                  // w00*eax (half0) / w10*eax (half1)
                float wb = wab.y;                  // w01 (half0) / w11' (half1)
                float va = half ? ey_[t] : 1.0f;
                float vb = half ? ez_[t] : 0.0f;
                float vc = half ? ew_[t] : 0.0f;
                float dot = fa_[t] * va + fb_[t] * vb + fc_[t] * vc;
                float w0s = half ? wb : wa;
                a0acc += w0s * dot;
                float m  = half ? wa : wb * fa_[t];
                float vx = half ? fa_[t] : ey_[t];
                float vy = half ? fb_[t] : ez_[t];
                float vz = half ? fc_[t] : ew_[t];
                a1x += m * vx; a1y += m * vy; a1z += m * vz;
            }
        }
    }

    __shared__ float red[4][256];
    float* r = red[wv];
    int c = (half << 5) + u;
    r[c] = a0acc;
    int b = 64 + c * 3;
    r[b] = a1x; r[b + 1] = a1y; r[b + 2] = a1z;
    __syncthreads();

    if (half == 0) {
        float acc = 0.f;
#pragma unroll 8
        for (int w = 0; w < 64; ++w) acc += r[w] * W2_0e[w * 32 + u];
        int o = node * 128 + u;
        out[o] = out[o] + SIN_CONV * acc;          // prefilled with COS_MIX*self
    } else {
        float c0 = 0.f, c1 = 0.f, c2 = 0.f;
#pragma unroll 8
        for (int w = 0; w < 64; ++w) {
            float bw = W2_1o[w * 32 + u];
            c0 += r[64 + w * 3 + 0] * bw;
            c1 += r[64 + w * 3 + 1] * bw;
            c2 += r[64 + w * 3 + 2] * bw;
        }
        int o = node * 128 + 32 + u * 3;
        out[o + 0] = out[o + 0] + SIN_CONV * c0;
        out[o + 1] = out[o + 1] + SIN_CONV * c1;
        out[o + 2] = out[o + 2] + SIN_CONV * c2;
    }
}

extern "C" void kernel_launch(void* const* d_in, const int* in_sizes, int n_in,
                              void* d_out, int out_size, void* d_ws, size_t ws_size,
                              hipStream_t stream) {
    const float* node_input  = (const float*)d_in[0];
    const float* edge_attr   = (const float*)d_in[1];
    const float* edge_scalar = (const float*)d_in[2];
    const float* W1_0e       = (const float*)d_in[3];
    const float* W1_1o       = (const float*)d_in[4];
    const float* W_mlp1      = (const float*)d_in[5];
    const float* W_mlp2      = (const float*)d_in[6];
    const float* Wp00        = (const float*)d_in[7];
    const float* Wp01        = (const float*)d_in[8];
    const float* Wp10        = (const float*)d_in[9];
    const float* Wp11        = (const float*)d_in[10];
    const float* W2_0e       = (const float*)d_in[11];
    const float* W2_1o       = (const float*)d_in[12];
    const int*   edge_src    = (const int*)d_in[13];
    const int*   edge_dst    = (const int*)d_in[14];
    float* ws   = (float*)d_ws;
    int*   wsI  = (int*)d_ws;
    uint32* wsU = (uint32*)d_ws;
    uint4* recp = (uint4*)(wsU + U_REC);
    float* outp = (float*)d_out;

    hipMemsetAsync(wsI + I_CNT, 0, (N_NODES + 1) * sizeof(int), stream);

    k1_fused<<<K1_NODE_BLOCKS + K1_CNT_BLOCKS + K1_PREP_BLOCKS, 256, 0, stream>>>(
        node_input, W1_0e, W1_1o, edge_dst, wsI + I_CNT,
        W_mlp1, W_mlp2, Wp00, Wp01, Wp10, Wp11, wsU + U_WF, ws + WS_FEATP, outp);
    csr_scan<<<1, 1024, 0, stream>>>(wsI + I_CNT, wsI + I_OFF);
    mlp_scatter<<<MLP_BLOCKS, 256, 0, stream>>>(edge_scalar, edge_attr,
                                                edge_src, edge_dst, wsI + I_OFF,
                                                wsU + U_WF, wsU + U_WBUF, recp);
    gather<<<N_NODES / 4, 256, 0, stream>>>(wsI + I_OFF, wsI + I_CNT, recp,
                                            wsU + U_WBUF, ws + WS_FEATP,
                                            W2_0e, W2_1o, outp);
}

// Round 12
// 120.009 us; speedup vs baseline: 1.2288x; 1.0127x over previous
//
#include <hip/hip_runtime.h>

typedef unsigned int uint32;
typedef unsigned short ushrt;
typedef __attribute__((ext_vector_type(4))) float f32x4;
typedef __attribute__((ext_vector_type(2))) float f32x2;
typedef __attribute__((ext_vector_type(8))) _Float16 halfx8;
typedef __attribute__((ext_vector_type(4))) uint32 uint32x4;

#define N_NODES 10000
#define N_EDGES 320000

// scales
#define SC_W1      0.17677669529663687f   // 1/sqrt(32)
#define SC_MLP1    0.35355339059327373f   // 1/sqrt(8)
#define SC_MLP2    0.125f                 // 1/sqrt(64)
#define INV_SQRT3  0.5773502691896258f
#define COS_MIX    0.9238795325112867f    // cos(pi/8)
#define SIN_CONV   0.04783542904563623f   // sin(pi/8) / sqrt(64)

// ws layout
#define WS_FEATP 0        // [N][128] floats, planar: f0 | f1x | f1y | f1z
#define I_CNT    1280000  // [N+1]
#define I_OFF    1290016  // [N+1]  (mutated by mlp_scatter; gather uses off-cnt)
#define U_REC    1300032  // [E] uint4: {ea.y, ea.z, ea.w bits, src}
#define U_WF     2580032  // 28 frags x 64 lanes x 4 uints
#define U_WBUF   2587200  // [E][32] uints = [E][64] fp8-pairs (128B rows), CSR order

__device__ __forceinline__ uint32 packh2(float a, float b) {
    _Float16 ha = (_Float16)a, hb = (_Float16)b;
    return (uint32)__builtin_bit_cast(unsigned short, ha) |
           ((uint32)__builtin_bit_cast(unsigned short, hb) << 16);
}
__device__ __forceinline__ unsigned short h16(float x) {
    _Float16 h = (_Float16)x;
    return __builtin_bit_cast(unsigned short, h);
}
__device__ __forceinline__ unsigned short pack_fp8_2(float a, float b) {
    return (unsigned short)(__builtin_amdgcn_cvt_pk_fp8_f32(a, b, 0, false) & 0xffff);
}
__device__ __forceinline__ float gelu_fast(float x) {
    float x2 = x * x;
    float z = x * __builtin_fmaf(0.03567740814f, x2, 0.7978845608f);
    float E = __builtin_amdgcn_exp2f(z * -2.885390082f);
    return x * __builtin_amdgcn_rcpf(1.0f + E);
}

// ================= K1: csr_count | prep_frags ====
#define K1_CNT_BLOCKS  1250
#define K1_PREP_BLOCKS 7
__global__ __launch_bounds__(256) void k1_fused(
        const int* __restrict__ edge_dst, int* __restrict__ cnt,
        const float* __restrict__ Wm1, const float* __restrict__ Wm2,
        const float* __restrict__ Wp00, const float* __restrict__ Wp01,
        const float* __restrict__ Wp10, const float* __restrict__ Wp11,
        uint32* __restrict__ wf) {
    int b = blockIdx.x;
    if (b < K1_CNT_BLOCKS) {
        int e = b * 256 + threadIdx.x;
        atomicAdd(&cnt[edge_dst[e]], 1);
    } else {
        int gid = (b - K1_CNT_BLOCKS) * 256 + threadIdx.x;
        int f = gid >> 6, lane = gid & 63;
        int kq = (lane >> 4) * 8;
        int c15 = lane & 15;
        float vals[8];
        if (f < 4) {
            int c = 16 * f + c15;
#pragma unroll
            for (int j = 0; j < 8; ++j) { int k = kq + j; vals[j] = (k < 8) ? Wm1[k * 64 + c] : 0.f; }
        } else if (f < 12) {
            int idx = f - 4, nt = idx >> 1, ks = idx & 1;
            int c = 16 * nt + c15;
#pragma unroll
            for (int j = 0; j < 8; ++j) { int k = 32 * ks + kq + j; vals[j] = Wm2[k * 64 + c]; }
        } else {
            int idx = f - 12, nt = idx >> 1, ks = idx & 1;
            int c = 16 * nt + c15;
            int u = c & 31, m = c >> 5;
            const float* W = (m == 0) ? Wp00 : (m == 1) ? Wp01 : (m == 2) ? Wp10 : Wp11;
            float sc = (m == 3) ? 0.125f * INV_SQRT3 : 0.125f;
#pragma unroll
            for (int j = 0; j < 8; ++j) { int k = 32 * ks + kq + j; vals[j] = W[k * 32 + u] * sc; }
        }
        uint32* o = wf + f * 256 + lane * 4;
#pragma unroll
        for (int w = 0; w < 4; ++w) o[w] = packh2(vals[2 * w], vals[2 * w + 1]);
    }
}

// ================= K2: csr_scan (single block, 1024 threads) =================
__global__ __launch_bounds__(1024) void csr_scan(const int* __restrict__ cnt,
                                                 int* __restrict__ off) {
    __shared__ int partial[1024];
    int t = threadIdx.x;
    const int CHUNK = 10;
    int base = t * CHUNK;
    int s = 0;
#pragma unroll
    for (int j = 0; j < CHUNK; ++j) {
        int idx = base + j;
        s += (idx < N_NODES) ? cnt[idx] : 0;
    }
    partial[t] = s;
    __syncthreads();
    for (int o = 1; o < 1024; o <<= 1) {
        int v = partial[t];
        int add = (t >= o) ? partial[t - o] : 0;
        __syncthreads();
        partial[t] = v + add;
        __syncthreads();
    }
    int run = (t > 0) ? partial[t - 1] : 0;
    for (int j = 0; j < CHUNK; ++j) {
        int idx = base + j;
        if (idx < N_NODES) {
            off[idx] = run;
            run += cnt[idx];
        }
    }
    if (t == 1023) off[N_NODES] = run;
}

// ================= K3: mlp_scatter + node_transform (co-resident) ===========
// Blocks [0, MLP_BLOCKS): MFMA MLP, fp8 rows (latency-bound waves).
// Blocks [MLP_BLOCKS, +2500): node_transform (short memory waves that fill
// the SIMD issue slots while mlp waves stall on MFMA/LDS/atomic latency).
#define MLP_BLOCKS 1250
#define K3_NODE_BLOCKS 2500
__global__ __launch_bounds__(256) void k3_fused(
        const float* __restrict__ edge_scalar, const float* __restrict__ edge_attr,
        const int* __restrict__ src_in, const int* __restrict__ dst_in,
        int* __restrict__ off,
        const uint32* __restrict__ wf,
        uint32* __restrict__ wbuf, uint4* __restrict__ rec,
        const float* __restrict__ x,
        const float* __restrict__ W1_0e, const float* __restrict__ W1_1o,
        float* __restrict__ featp, float* __restrict__ out) {
    __shared__ unsigned short sh[4][1024];   // mlp: per-wave 16x64 f16 tile
    __shared__ uint32 ob[4][512];            // mlp: per-wave 16 rows x 32 uints
    __shared__ float eaxs[4][16];
    __shared__ int   poss[4][16];
    __shared__ float xrow[4][128];           // node branch

    int lane = threadIdx.x & 63;
    int wvq = threadIdx.x >> 6;

    if (blockIdx.x >= MLP_BLOCKS) {
        // ---- node_transform ----
        int node = (blockIdx.x - MLP_BLOCKS) * 4 + wvq;
        float2 v = *(const float2*)(x + (size_t)node * 128 + lane * 2);
        xrow[wvq][lane * 2]     = v.x;
        xrow[wvq][lane * 2 + 1] = v.y;
        __syncthreads();
        const float* sx = xrow[wvq];
        int w = lane;
        float f0 = 0.f, f1x = 0.f, f1y = 0.f, f1z = 0.f;
#pragma unroll
        for (int u = 0; u < 32; ++u) {
            float w0 = W1_0e[u * 64 + w];
            float w1 = W1_1o[u * 64 + w];
            f0  += sx[u] * w0;
            f1x += sx[32 + u * 3 + 0] * w1;
            f1y += sx[32 + u * 3 + 1] * w1;
            f1z += sx[32 + u * 3 + 2] * w1;
        }
        f0 *= SC_W1; f1x *= SC_W1; f1y *= SC_W1; f1z *= SC_W1;
        if (w < 32) {
            featp[node * 128 + w]      = f0;
            featp[node * 128 + 32 + w] = f1x;
            featp[node * 128 + 64 + w] = f1y;
            featp[node * 128 + 96 + w] = f1z;
        } else {
            int ww = w - 32;
            out[node * 128 + ww] = COS_MIX * f0;
            out[node * 128 + 32 + ww * 3 + 0] = COS_MIX * f1x;
            out[node * 128 + 32 + ww * 3 + 1] = COS_MIX * f1y;
            out[node * 128 + 32 + ww * 3 + 2] = COS_MIX * f1z;
        }
        return;
    }

    // ---- mlp_scatter ----
    int wave_id = blockIdx.x * 4 + wvq;
    int kq = (lane >> 4) * 8;
    int r15 = lane & 15;

    const uint32x4* wfp = (const uint32x4*)wf;
    halfx8 wb1[4], wb2[4][2], wbp[8][2];
#pragma unroll
    for (int nt = 0; nt < 4; ++nt)
        wb1[nt] = __builtin_bit_cast(halfx8, wfp[nt * 64 + lane]);
#pragma unroll
    for (int nt = 0; nt < 4; ++nt)
#pragma unroll
        for (int ks = 0; ks < 2; ++ks)
            wb2[nt][ks] = __builtin_bit_cast(halfx8, wfp[(4 + nt * 2 + ks) * 64 + lane]);
#pragma unroll
    for (int nt = 0; nt < 8; ++nt)
#pragma unroll
        for (int ks = 0; ks < 2; ++ks)
            wbp[nt][ks] = __builtin_bit_cast(halfx8, wfp[(12 + nt * 2 + ks) * 64 + lane]);

    const f32x4 z4 = {0.f, 0.f, 0.f, 0.f};
    unsigned short* shw = sh[wvq];
    uint32* obw = ob[wvq];
    unsigned short* obw16 = (unsigned short*)obw;

    for (int g = wave_id; g < N_EDGES / 16; g += MLP_BLOCKS * 4) {
        int e0 = g * 16;

        halfx8 a0 = (halfx8)0;
        if (lane < 16) {
            int e = e0 + lane;
            const float* esp = edge_scalar + (size_t)e * 8;
            float4 p = *(const float4*)esp;
            float4 q = *(const float4*)(esp + 4);
            float4 av = *(const float4*)(edge_attr + (size_t)e * 4);
            int dn = dst_in[e];
            int sn = src_in[e];
            int pos = atomicAdd(&off[dn], 1);
            poss[wvq][lane] = pos;
            eaxs[wvq][lane] = av.x;
            uint4 rv;
            rv.x = __float_as_uint(av.y);
            rv.y = __float_as_uint(av.z);
            rv.z = __float_as_uint(av.w);
            rv.w = (uint32)sn;
            rec[pos] = rv;
            a0[0] = (_Float16)p.x; a0[1] = (_Float16)p.y;
            a0[2] = (_Float16)p.z; a0[3] = (_Float16)p.w;
            a0[4] = (_Float16)q.x; a0[5] = (_Float16)q.y;
            a0[6] = (_Float16)q.z; a0[7] = (_Float16)q.w;
        }

        // h1 GEMM
        f32x4 acc1[4];
#pragma unroll
        for (int nt = 0; nt < 4; ++nt)
            acc1[nt] = __builtin_amdgcn_mfma_f32_16x16x32_f16(a0, wb1[nt], z4, 0, 0, 0);
#pragma unroll
        for (int nt = 0; nt < 4; ++nt)
#pragma unroll
            for (int i = 0; i < 4; ++i) {
                float gv = gelu_fast(acc1[nt][i] * SC_MLP1);
                int rr = (lane >> 4) * 4 + i;
                int ix = rr * 64 + 16 * nt + r15;
                shw[ix ^ ((rr & 7) << 3)] = h16(gv);
            }
        halfx8 a1[2];
#pragma unroll
        for (int ks = 0; ks < 2; ++ks) {
            int ix = r15 * 64 + 32 * ks + kq;
            a1[ks] = __builtin_bit_cast(halfx8,
                       *(const uint32x4*)&shw[ix ^ ((r15 & 7) << 3)]);
        }

        // h2 GEMM
        f32x4 acc2[4];
#pragma unroll
        for (int nt = 0; nt < 4; ++nt) {
            acc2[nt] = __builtin_amdgcn_mfma_f32_16x16x32_f16(a1[0], wb2[nt][0], z4, 0, 0, 0);
            acc2[nt] = __builtin_amdgcn_mfma_f32_16x16x32_f16(a1[1], wb2[nt][1], acc2[nt], 0, 0, 0);
        }
#pragma unroll
        for (int nt = 0; nt < 4; ++nt)
#pragma unroll
            for (int i = 0; i < 4; ++i) {
                float gv = gelu_fast(acc2[nt][i] * SC_MLP2);
                int rr = (lane >> 4) * 4 + i;
                int ix = rr * 64 + 16 * nt + r15;
                shw[ix ^ ((rr & 7) << 3)] = h16(gv);
            }
        halfx8 a2[2];
#pragma unroll
        for (int ks = 0; ks < 2; ++ks) {
            int ix = r15 * 64 + 32 * ks + kq;
            a2[ks] = __builtin_bit_cast(halfx8,
                       *(const uint32x4*)&shw[ix ^ ((r15 & 7) << 3)]);
        }

        // projection GEMM
        f32x4 accp[8];
#pragma unroll
        for (int nt = 0; nt < 8; ++nt) {
            accp[nt] = __builtin_amdgcn_mfma_f32_16x16x32_f16(a2[0], wbp[nt][0], z4, 0, 0, 0);
            accp[nt] = __builtin_amdgcn_mfma_f32_16x16x32_f16(a2[1], wbp[nt][1], accp[nt], 0, 0, 0);
        }

        // fold ea.x, pack fp8 pairs into LDS staging
#pragma unroll
        for (int i = 0; i < 4; ++i) {
            int rr = (lane >> 4) * 4 + i;
            float eax = eaxs[wvq][rr];
            unsigned short* orow = obw16 + rr * 64;
            orow[r15]      = pack_fp8_2(accp[0][i] * eax, accp[2][i]);
            orow[16 + r15] = pack_fp8_2(accp[1][i] * eax, accp[3][i]);
            orow[32 + r15] = pack_fp8_2(accp[4][i] * eax, accp[6][i]);
            orow[48 + r15] = pack_fp8_2(accp[5][i] * eax, accp[7][i]);
        }
        // store full rows: each row = 8 lanes x dwordx4 = 128B = one L2 line
#pragma unroll
        for (int pass = 0; pass < 2; ++pass) {
            int r = pass * 8 + (lane >> 3);
            int pos = poss[wvq][r];
            int c4 = (lane & 7) * 4;
            uint32x4 v = *(const uint32x4*)&obw[r * 32 + c4];
            *(uint32x4*)(wbuf + (size_t)pos * 32 + c4) = v;
        }
    }
}

// ================= K4: gather (all-linear streams + featp table) =============
__global__ __launch_bounds__(256) void gather(const int* __restrict__ off,
                                              const int* __restrict__ cnt,
                                              const uint4* __restrict__ rec,
                                              const uint32* __restrict__ wbuf,
                                              const float* __restrict__ featp,
                                              const float* __restrict__ W2_0e,
                                              const float* __restrict__ W2_1o,
                                              float* __restrict__ out) {
    int wv = threadIdx.x >> 6;
    int lane = threadIdx.x & 63;
    int node = blockIdx.x * 4 + wv;
    int u = lane & 31;
    int half = lane >> 5;

    int end = __builtin_amdgcn_readfirstlane(off[node]);   // off mutated = end
    int beg = end - __builtin_amdgcn_readfirstlane(cnt[node]);

    float a0acc = 0.f, a1x = 0.f, a1y = 0.f, a1z = 0.f;
    int offA = u + half * 32, offB = 64 + u, offC = 96 + u;
    const ushrt* wbuf16 = (const ushrt*)wbuf;
    int uslot = (half << 5) + u;

    for (int i0 = beg; i0 < end; i0 += 64) {
        int nn = end - i0;
        if (nn > 64) nn = 64;
        int idx = i0 + ((lane < nn) ? lane : 0);
        uint4 rv = rec[idx];                       // coalesced batch of 64 records
        int eyv = (int)rv.x, ezv = (int)rv.y, ewv = (int)rv.z, svv = (int)rv.w;
        for (int j0 = 0; j0 < nn; j0 += 4) {
            uint32 wl_[4];
            float fa_[4], fb_[4], fc_[4], ey_[4], ez_[4], ew_[4];
#pragma unroll
            for (int t = 0; t < 4; ++t) {
                int j = j0 + t;
                int jc = (j < nn) ? j : nn - 1;
                ey_[t] = __uint_as_float((uint32)__builtin_amdgcn_readlane(eyv, jc));
                ez_[t] = __uint_as_float((uint32)__builtin_amdgcn_readlane(ezv, jc));
                ew_[t] = __uint_as_float((uint32)__builtin_amdgcn_readlane(ewv, jc));
                int s  = __builtin_amdgcn_readlane(svv, jc);
                uint32 wl = (uint32)wbuf16[(size_t)(i0 + jc) * 64 + uslot]; // linear 128B rows
                wl_[t] = (j < nn) ? wl : 0u;
                const float* fp = featp + (size_t)s * 128;
                fa_[t] = fp[offA];
                fb_[t] = fp[offB];
                fc_[t] = fp[offC];
            }
#pragma unroll
            for (int t = 0; t < 4; ++t) {
                f32x2 wab = __builtin_amdgcn_cvt_pk_f32_fp8((int)wl_[t], false);
                float wa = wab.x;
                float wb = wab.y;
                float va = half ? ey_[t] : 1.0f;
                float vb = half ? ez_[t] : 0.0f;
                float vc = half ? ew_[t] : 0.0f;
                float dot = fa_[t] * va + fb_[t] * vb + fc_[t] * vc;
                float w0s = half ? wb : wa;
                a0acc += w0s * dot;
                float m  = half ? wa : wb * fa_[t];
                float vx = half ? fa_[t] : ey_[t];
                float vy = half ? fb_[t] : ez_[t];
                float vz = half ? fc_[t] : ew_[t];
                a1x += m * vx; a1y += m * vy; a1z += m * vz;
            }
        }
    }

    __shared__ float red[4][256];
    float* r = red[wv];
    int c = (half << 5) + u;
    r[c] = a0acc;
    int b = 64 + c * 3;
    r[b] = a1x; r[b + 1] = a1y; r[b + 2] = a1z;
    __syncthreads();

    if (half == 0) {
        float acc = 0.f;
#pragma unroll 8
        for (int w = 0; w < 64; ++w) acc += r[w] * W2_0e[w * 32 + u];
        int o = node * 128 + u;
        out[o] = out[o] + SIN_CONV * acc;          // prefilled with COS_MIX*self
    } else {
        float c0 = 0.f, c1 = 0.f, c2 = 0.f;
#pragma unroll 8
        for (int w = 0; w < 64; ++w) {
            float bw = W2_1o[w * 32 + u];
            c0 += r[64 + w * 3 + 0] * bw;
            c1 += r[64 + w * 3 + 1] * bw;
            c2 += r[64 + w * 3 + 2] * bw;
        }
        int o = node * 128 + 32 + u * 3;
        out[o + 0] = out[o + 0] + SIN_CONV * c0;
        out[o + 1] = out[o + 1] + SIN_CONV * c1;
        out[o + 2] = out[o + 2] + SIN_CONV * c2;
    }
}

extern "C" void kernel_launch(void* const* d_in, const int* in_sizes, int n_in,
                              void* d_out, int out_size, void* d_ws, size_t ws_size,
                              hipStream_t stream) {
    const float* node_input  = (const float*)d_in[0];
    const float* edge_attr   = (const float*)d_in[1];
    const float* edge_scalar = (const float*)d_in[2];
    const float* W1_0e       = (const float*)d_in[3];
    const float* W1_1o       = (const float*)d_in[4];
    const float* W_mlp1      = (const float*)d_in[5];
    const float* W_mlp2      = (const float*)d_in[6];
    const float* Wp00        = (const float*)d_in[7];
    const float* Wp01        = (const float*)d_in[8];
    const float* Wp10        = (const float*)d_in[9];
    const float* Wp11        = (const float*)d_in[10];
    const float* W2_0e       = (const float*)d_in[11];
    const float* W2_1o       = (const float*)d_in[12];
    const int*   edge_src    = (const int*)d_in[13];
    const int*   edge_dst    = (const int*)d_in[14];
    float* ws   = (float*)d_ws;
    int*   wsI  = (int*)d_ws;
    uint32* wsU = (uint32*)d_ws;
    uint4* recp = (uint4*)(wsU + U_REC);
    float* outp = (float*)d_out;

    hipMemsetAsync(wsI + I_CNT, 0, (N_NODES + 1) * sizeof(int), stream);

    k1_fused<<<K1_CNT_BLOCKS + K1_PREP_BLOCKS, 256, 0, stream>>>(
        edge_dst, wsI + I_CNT,
        W_mlp1, W_mlp2, Wp00, Wp01, Wp10, Wp11, wsU + U_WF);
    csr_scan<<<1, 1024, 0, stream>>>(wsI + I_CNT, wsI + I_OFF);
    k3_fused<<<MLP_BLOCKS + K3_NODE_BLOCKS, 256, 0, stream>>>(
        edge_scalar, edge_attr, edge_src, edge_dst, wsI + I_OFF,
        wsU + U_WF, wsU + U_WBUF, recp,
        node_input, W1_0e, W1_1o, ws + WS_FEATP, outp);
    gather<<<N_NODES / 4, 256, 0, stream>>>(wsI + I_OFF, wsI + I_CNT, recp,
                                            wsU + U_WBUF, ws + WS_FEATP,
                                            W2_0e, W2_1o, outp);
}